// Round 1
// baseline (829.536 us; speedup 1.0000x reference)
//
#include <hip/hip_runtime.h>

typedef _Float16 f16;
typedef _Float16 f16x4 __attribute__((ext_vector_type(4)));
typedef _Float16 f16x8 __attribute__((ext_vector_type(8)));
typedef float f32x4 __attribute__((ext_vector_type(4)));

#define DEVI __device__ __forceinline__

static constexpr int CAP = 64;   // slots per row; P(deg>64 | lambda=16) ~ 1e-19

DEVI void g2l16(const void* g, void* l) {
  __builtin_amdgcn_global_load_lds(
      (const __attribute__((address_space(1))) void*)g,
      (__attribute__((address_space(3))) void*)l, 16, 0, 0);
}

DEVI f16x8 cvt8(float4 a, float4 b) {
  f16x8 r;
  r[0] = (f16)a.x; r[1] = (f16)a.y; r[2] = (f16)a.z; r[3] = (f16)a.w;
  r[4] = (f16)b.x; r[5] = (f16)b.y; r[6] = (f16)b.z; r[7] = (f16)b.w;
  return r;
}

// ---------------- W transpose + cast: WT[n][k] = (f16)W[k][n] ----------------
__global__ __launch_bounds__(256)
void prep_w(const float* __restrict__ W1, const float* __restrict__ W2,
            const float* __restrict__ W3, f16* __restrict__ WT1,
            f16* __restrict__ WT2, f16* __restrict__ WT3) {
  int t = blockIdx.x * 256 + threadIdx.x;
  if (t < 131072) {                       // W1: 512x256 -> WT1: 256x512
    int n = t >> 9, k = t & 511;
    WT1[t] = (f16)W1[k * 256 + n];
  } else if (t < 131072 + 65536) {        // W2: 256x256 -> WT2: 256x256
    int u = t - 131072; int n = u >> 8, k = u & 255;
    WT2[u] = (f16)W2[k * 256 + n];
  } else if (t < 131072 + 65536 + 16384) {// W3: 256x64 -> WT3: 64x256
    int u = t - 131072 - 65536; int n = u >> 8, k = u & 255;
    WT3[u] = (f16)W3[k * 64 + n];
  }
}

// ---------------- bucket build: slots[r][p] = (col, val) ----------------
__global__ __launch_bounds__(256)
void build_slots(const int* __restrict__ row, const int* __restrict__ col,
                 const float* __restrict__ vals, int* __restrict__ cnt,
                 int2* __restrict__ slots, int E) {
  int e = blockIdx.x * 256 + threadIdx.x;
  if (e >= E) return;
  int r = row[e];
  int p = atomicAdd(&cnt[r], 1);
  if (p < CAP) slots[(size_t)r * CAP + p] = make_int2(col[e], __float_as_int(vals[e]));
}

// ---------------- GEMM: C[M][N](f16) = A[M][K] @ WT[N][K]^T + bias ----------------
// BM=128, BK=32, 4 waves in 2x2, each wave 4 x (BN/32) tiles of mfma 16x16x32 f16
template <int BN, bool AF32>
__global__ __launch_bounds__(256)
void gemm_kern(const void* __restrict__ Ap, const f16* __restrict__ WT,
               const float* __restrict__ bias, f16* __restrict__ C,
               int M, int K, int N) {
  constexpr int BM = 128;
  constexpr int NT = BN / 32;
  __shared__ f16 As[BM * 32];
  __shared__ f16 Bs[BN * 32];

  const int tid = threadIdx.x;
  const int wave = tid >> 6, lane = tid & 63;
  const int wm = wave >> 1, wn = wave & 1;
  const int quad = lane >> 4, l16 = lane & 15;
  const int bm = blockIdx.x, bn = blockIdx.y;
  const int r0 = bm * BM;

  f32x4 acc[4][NT];
#pragma unroll
  for (int mt = 0; mt < 4; ++mt)
#pragma unroll
    for (int nt = 0; nt < NT; ++nt) {
      f32x4 z = {0.f, 0.f, 0.f, 0.f};
      acc[mt][nt] = z;
    }

  const int kiters = K >> 5;
  for (int kb = 0; kb < kiters; ++kb) {
    // ---- stage A tile (BM x 32) ----
    if constexpr (AF32) {
      const float* Af = (const float*)Ap;
      int row = r0 + (tid >> 1);
      row = min(row, M - 1);
      const int half = tid & 1;
      const float4* gp = (const float4*)(Af + (size_t)row * K + kb * 32 + half * 16);
      float4 v0 = gp[0], v1 = gp[1], v2 = gp[2], v3 = gp[3];
      f16x8* dst = (f16x8*)&As[(tid >> 1) * 32 + half * 16];
      dst[0] = cvt8(v0, v1);
      dst[1] = cvt8(v2, v3);
    } else {
      const f16* Ah = (const f16*)Ap;
#pragma unroll
      for (int t = 0; t < 2; ++t) {
        int inst = wave * 2 + t;
        int row = r0 + inst * 16 + (lane >> 2);
        row = min(row, M - 1);
        const f16* gp = Ah + (size_t)row * K + kb * 32 + (lane & 3) * 8;
        g2l16(gp, &As[inst * 16 * 32]);
      }
    }
    // ---- stage B tile (BN x 32) from WT (already [n][k]) ----
#pragma unroll
    for (int t = 0; t < BN / 64; ++t) {
      int inst = wave * (BN / 64) + t;
      int n = bn * BN + inst * 16 + (lane >> 2);
      const f16* gp = WT + (size_t)n * K + kb * 32 + (lane & 3) * 8;
      g2l16(gp, &Bs[inst * 16 * 32]);
    }
    __syncthreads();

    f16x8 af[4], bf[NT];
#pragma unroll
    for (int mt = 0; mt < 4; ++mt)
      af[mt] = *(const f16x8*)&As[(wm * 64 + mt * 16 + l16) * 32 + quad * 8];
#pragma unroll
    for (int nt = 0; nt < NT; ++nt)
      bf[nt] = *(const f16x8*)&Bs[(wn * (BN / 2) + nt * 16 + l16) * 32 + quad * 8];
#pragma unroll
    for (int mt = 0; mt < 4; ++mt)
#pragma unroll
      for (int nt = 0; nt < NT; ++nt)
        acc[mt][nt] = __builtin_amdgcn_mfma_f32_16x16x32_f16(af[mt], bf[nt], acc[mt][nt], 0, 0, 0);
    __syncthreads();
  }

  // ---- epilogue: + bias, store f16 ----
  float bv[NT];
#pragma unroll
  for (int nt = 0; nt < NT; ++nt)
    bv[nt] = bias[bn * BN + wn * (BN / 2) + nt * 16 + l16];
#pragma unroll
  for (int mt = 0; mt < 4; ++mt) {
#pragma unroll
    for (int nt = 0; nt < NT; ++nt) {
      int colg = bn * BN + wn * (BN / 2) + nt * 16 + l16;
#pragma unroll
      for (int r = 0; r < 4; ++r) {
        int grow = r0 + wm * 64 + mt * 16 + quad * 4 + r;
        if (grow < M)
          C[(size_t)grow * N + colg] = (f16)(acc[mt][nt][r] + bv[nt]);
      }
    }
  }
}

// ---------------- SpMM (F=256) + ReLU: H[i] = relu(sum vals*T[col]) ----------------
__global__ __launch_bounds__(256)
void spmm_relu256(const f16* __restrict__ T, const int2* __restrict__ slots,
                  const int* __restrict__ cnt, f16* __restrict__ H, int nrows) {
  const int wave = threadIdx.x >> 6, lane = threadIdx.x & 63;
  const int i = blockIdx.x * 4 + wave;
  if (i >= nrows) return;
  const int c = min(cnt[i], CAP);
  const int2* sl = slots + (size_t)i * CAP;
  float a0 = 0.f, a1 = 0.f, a2 = 0.f, a3 = 0.f;
  int j = 0;
  for (; j + 4 <= c; j += 4) {
    int2 e0 = sl[j], e1 = sl[j + 1], e2 = sl[j + 2], e3 = sl[j + 3];
    f16x4 u0 = ((const f16x4*)(T + (size_t)e0.x * 256))[lane];
    f16x4 u1 = ((const f16x4*)(T + (size_t)e1.x * 256))[lane];
    f16x4 u2 = ((const f16x4*)(T + (size_t)e2.x * 256))[lane];
    f16x4 u3 = ((const f16x4*)(T + (size_t)e3.x * 256))[lane];
    float v0 = __int_as_float(e0.y), v1 = __int_as_float(e1.y);
    float v2 = __int_as_float(e2.y), v3 = __int_as_float(e3.y);
    a0 += v0 * (float)u0.x + v1 * (float)u1.x + v2 * (float)u2.x + v3 * (float)u3.x;
    a1 += v0 * (float)u0.y + v1 * (float)u1.y + v2 * (float)u2.y + v3 * (float)u3.y;
    a2 += v0 * (float)u0.z + v1 * (float)u1.z + v2 * (float)u2.z + v3 * (float)u3.z;
    a3 += v0 * (float)u0.w + v1 * (float)u1.w + v2 * (float)u2.w + v3 * (float)u3.w;
  }
  for (; j < c; ++j) {
    int2 e = sl[j];
    f16x4 u = ((const f16x4*)(T + (size_t)e.x * 256))[lane];
    float v = __int_as_float(e.y);
    a0 += v * (float)u.x; a1 += v * (float)u.y;
    a2 += v * (float)u.z; a3 += v * (float)u.w;
  }
  f16x4 o;
  o.x = (f16)fmaxf(a0, 0.f); o.y = (f16)fmaxf(a1, 0.f);
  o.z = (f16)fmaxf(a2, 0.f); o.w = (f16)fmaxf(a3, 0.f);
  ((f16x4*)(H + (size_t)i * 256))[lane] = o;
}

// ---------------- SpMM (F=64), fp32 out, no activation ----------------
__global__ __launch_bounds__(256)
void spmm_out64(const f16* __restrict__ T, const int2* __restrict__ slots,
                const int* __restrict__ cnt, float* __restrict__ out, int nrows) {
  const int wave = threadIdx.x >> 6, lane = threadIdx.x & 63;
  const int i = blockIdx.x * 4 + wave;
  if (i >= nrows) return;
  const int c = min(cnt[i], CAP);
  const int2* sl = slots + (size_t)i * CAP;
  float a = 0.f;
  int j = 0;
  for (; j + 4 <= c; j += 4) {
    int2 e0 = sl[j], e1 = sl[j + 1], e2 = sl[j + 2], e3 = sl[j + 3];
    float u0 = (float)T[(size_t)e0.x * 64 + lane];
    float u1 = (float)T[(size_t)e1.x * 64 + lane];
    float u2 = (float)T[(size_t)e2.x * 64 + lane];
    float u3 = (float)T[(size_t)e3.x * 64 + lane];
    a += __int_as_float(e0.y) * u0 + __int_as_float(e1.y) * u1
       + __int_as_float(e2.y) * u2 + __int_as_float(e3.y) * u3;
  }
  for (; j < c; ++j) {
    int2 e = sl[j];
    a += __int_as_float(e.y) * (float)T[(size_t)e.x * 64 + lane];
  }
  out[(size_t)i * 64 + lane] = a;
}

extern "C" void kernel_launch(void* const* d_in, const int* in_sizes, int n_in,
                              void* d_out, int out_size, void* d_ws, size_t ws_size,
                              hipStream_t stream) {
  const float* x    = (const float*)d_in[0];
  const int*   row  = (const int*)d_in[1];
  const int*   col  = (const int*)d_in[2];
  const float* vals = (const float*)d_in[3];
  const float* W1   = (const float*)d_in[4];
  const float* b1   = (const float*)d_in[5];
  const float* W2   = (const float*)d_in[6];
  const float* b2   = (const float*)d_in[7];
  const float* W3   = (const float*)d_in[8];
  const float* b3   = (const float*)d_in[9];
  float* out = (float*)d_out;

  const int N = in_sizes[0] / 512;   // 100000
  const int E = in_sizes[1];         // 1600000

  // workspace layout (~153 MiB total)
  char* ws = (char*)d_ws;
  const size_t MiB = 1ull << 20;
  int*  cnt   = (int*)ws;                   // 0.4 MB
  int2* slots = (int2*)(ws + 1 * MiB);      // N*64*8 = 51.2 MB
  f16*  WT1   = (f16*)(ws + 52 * MiB);      // 0.26 MB
  f16*  WT2   = WT1 + 256 * 512;
  f16*  WT3   = WT2 + 256 * 256;
  f16*  T     = (f16*)(ws + 53 * MiB);      // N*256*2 = 51.2 MB
  f16*  H     = (f16*)(ws + 104 * MiB);     // N*256*2 = 51.2 MB

  hipMemsetAsync(cnt, 0, (size_t)N * sizeof(int), stream);
  prep_w<<<(131072 + 65536 + 16384 + 255) / 256, 256, 0, stream>>>(W1, W2, W3, WT1, WT2, WT3);
  build_slots<<<(E + 255) / 256, 256, 0, stream>>>(row, col, vals, cnt, slots, E);

  dim3 g12((N + 127) / 128, 2);
  dim3 g3((N + 127) / 128, 1);
  dim3 gs((N + 3) / 4);

  // layer 1
  gemm_kern<128, true><<<g12, 256, 0, stream>>>(x, WT1, b1, T, N, 512, 256);
  spmm_relu256<<<gs, 256, 0, stream>>>(T, slots, cnt, H, N);
  // layer 2
  gemm_kern<128, false><<<g12, 256, 0, stream>>>(H, WT2, b2, T, N, 256, 256);
  spmm_relu256<<<gs, 256, 0, stream>>>(T, slots, cnt, H, N);
  // layer 3
  gemm_kern<64, false><<<g3, 256, 0, stream>>>(H, WT3, b3, T, N, 256, 64);
  spmm_out64<<<gs, 256, 0, stream>>>(T, slots, cnt, out, N);
}